// Round 1
// baseline (603.946 us; speedup 1.0000x reference)
//
#include <hip/hip_runtime.h>

// AlignOnlySubLayer: out[b,m,d] = main[b,m,d] - sum_c softmax_m(C·M^T)[c,m] * C[c,d]
// B=8, Lc=2048, Lm=2048, D=128, fp32.
// Pass 1: L[b,c] = sum_m exp(S[b,c,m] - 40)   (constant-shift softmax; S in [-70,70] so safe)
// Pass 2: out = main - sum_c (exp(S-40)/L[c]) * C[c,:]

#define BATCH 8
#define LC 2048
#define LM 2048
#define DD 128
#define SHIFT 40.0f
#define MCHUNKS 4
#define MT_PER_CHUNK ((LM / 64) / MCHUNKS)  // 8 tiles of 64 m per chunk

__global__ __launch_bounds__(256) void zero_kernel(float* __restrict__ p, int n) {
    int i = blockIdx.x * 256 + threadIdx.x;
    if (i < n) p[i] = 0.0f;
}

// grid = BATCH * (LC/64) * MCHUNKS blocks, 256 threads.
// Each block: one 64-row c-tile of one batch, one 512-wide m-chunk; atomicAdd partial L.
__global__ __launch_bounds__(256) void stats_kernel(const float* __restrict__ ctx,
                                                    const float* __restrict__ mn,
                                                    float* __restrict__ Lg) {
    __shared__ float Cs[64][129];  // pad 1: compute reads are 2-way max (free)
    __shared__ float Ms[64][129];

    int bid = blockIdx.x;
    int mc = bid % MCHUNKS;
    int ct = (bid / MCHUNKS) % (LC / 64);
    int b  = bid / (MCHUNKS * (LC / 64));
    int t = threadIdx.x;

    // Stage context tile (64 x 128, contiguous in global) once.
    const float* Cbase = ctx + ((size_t)b * LC + (size_t)ct * 64) * DD;
    for (int i = t; i < 64 * 128 / 4; i += 256) {
        float4 v = ((const float4*)Cbase)[i];
        int f = i * 4; int r = f >> 7; int c = f & 127;
        Cs[r][c + 0] = v.x; Cs[r][c + 1] = v.y; Cs[r][c + 2] = v.z; Cs[r][c + 3] = v.w;
    }

    int ty = t >> 4;   // 0..15 -> c rows 4*ty..4*ty+3
    int tx = t & 15;   // 0..15 -> m cols 4*tx..4*tx+3
    float ls[4] = {0.f, 0.f, 0.f, 0.f};

    for (int mt = 0; mt < MT_PER_CHUNK; ++mt) {
        int m0 = (mc * MT_PER_CHUNK + mt) * 64;
        __syncthreads();  // protect Ms from previous iter readers
        const float* Mbase = mn + ((size_t)b * LM + m0) * DD;
        for (int i = t; i < 64 * 128 / 4; i += 256) {
            float4 v = ((const float4*)Mbase)[i];
            int f = i * 4; int r = f >> 7; int c = f & 127;
            Ms[r][c + 0] = v.x; Ms[r][c + 1] = v.y; Ms[r][c + 2] = v.z; Ms[r][c + 3] = v.w;
        }
        __syncthreads();

        float acc[4][4] = {};
        #pragma unroll 4
        for (int k = 0; k < 128; ++k) {
            float a[4], bb[4];
            #pragma unroll
            for (int i = 0; i < 4; ++i) a[i] = Cs[4 * ty + i][k];
            #pragma unroll
            for (int j = 0; j < 4; ++j) bb[j] = Ms[4 * tx + j][k];
            #pragma unroll
            for (int i = 0; i < 4; ++i)
                #pragma unroll
                for (int j = 0; j < 4; ++j)
                    acc[i][j] += a[i] * bb[j];
        }
        #pragma unroll
        for (int i = 0; i < 4; ++i) {
            float s = 0.f;
            #pragma unroll
            for (int j = 0; j < 4; ++j) s += __expf(acc[i][j] - SHIFT);
            ls[i] += s;
        }
    }

    // Reduce over the 16 lanes (tx) sharing each c-row, then one atomicAdd per row.
    #pragma unroll
    for (int i = 0; i < 4; ++i) {
        float v = ls[i];
        v += __shfl_xor(v, 1);
        v += __shfl_xor(v, 2);
        v += __shfl_xor(v, 4);
        v += __shfl_xor(v, 8);
        ls[i] = v;
    }
    if (tx == 0) {
        int cbase = ct * 64 + 4 * ty;
        #pragma unroll
        for (int i = 0; i < 4; ++i)
            atomicAdd(&Lg[(size_t)b * LC + cbase + i], ls[i]);
    }
}

// grid = BATCH * (LM/64) blocks, 256 threads. Each block owns a 64-m tile, loops all c-tiles.
__global__ __launch_bounds__(256) void attend_kernel(const float* __restrict__ ctx,
                                                     const float* __restrict__ mn,
                                                     const float* __restrict__ Lg,
                                                     float* __restrict__ out) {
    __shared__ float Mt[64][129];
    __shared__ float Ct[64][129];
    __shared__ float Ps[64][65];
    __shared__ float invLs[64];

    int bid = blockIdx.x;
    int mt = bid % (LM / 64);
    int b  = bid / (LM / 64);
    int t = threadIdx.x;
    int m0 = mt * 64;

    const float* Mbase = mn + ((size_t)b * LM + m0) * DD;
    for (int i = t; i < 64 * 128 / 4; i += 256) {
        float4 v = ((const float4*)Mbase)[i];
        int f = i * 4; int r = f >> 7; int c = f & 127;
        Mt[r][c + 0] = v.x; Mt[r][c + 1] = v.y; Mt[r][c + 2] = v.z; Mt[r][c + 3] = v.w;
    }

    int ty = t >> 4, tx = t & 15;
    float acc[4][8] = {};  // rows m=4*ty+i, cols d=tx+16*j

    for (int ctile = 0; ctile < LC / 64; ++ctile) {
        __syncthreads();  // protect Ct/Ps from previous iteration readers
        const float* Cbase = ctx + ((size_t)b * LC + (size_t)ctile * 64) * DD;
        for (int i = t; i < 64 * 128 / 4; i += 256) {
            float4 v = ((const float4*)Cbase)[i];
            int f = i * 4; int r = f >> 7; int c = f & 127;
            Ct[r][c + 0] = v.x; Ct[r][c + 1] = v.y; Ct[r][c + 2] = v.z; Ct[r][c + 3] = v.w;
        }
        if (t < 64) invLs[t] = 1.0f / Lg[(size_t)b * LC + ctile * 64 + t];
        __syncthreads();

        // S^T tile: s[i][j] = S[c = ctile*64+4*tx+j, m = m0+4*ty+i]
        float s[4][4] = {};
        #pragma unroll 4
        for (int k = 0; k < 128; ++k) {
            float a[4], bb[4];
            #pragma unroll
            for (int i = 0; i < 4; ++i) a[i] = Mt[4 * ty + i][k];
            #pragma unroll
            for (int j = 0; j < 4; ++j) bb[j] = Ct[4 * tx + j][k];
            #pragma unroll
            for (int i = 0; i < 4; ++i)
                #pragma unroll
                for (int j = 0; j < 4; ++j)
                    s[i][j] += a[i] * bb[j];
        }
        #pragma unroll
        for (int i = 0; i < 4; ++i)
            #pragma unroll
            for (int j = 0; j < 4; ++j)
                Ps[4 * ty + i][4 * tx + j] = __expf(s[i][j] - SHIFT) * invLs[4 * tx + j];
        __syncthreads();

        // O[m][d] += P[m][c] * C[c][d]; Ct row read is bank-spread via tx+16*j
        #pragma unroll 4
        for (int k = 0; k < 64; ++k) {
            float p[4], cv[8];
            #pragma unroll
            for (int i = 0; i < 4; ++i) p[i] = Ps[4 * ty + i][k];
            #pragma unroll
            for (int j = 0; j < 8; ++j) cv[j] = Ct[k][tx + 16 * j];
            #pragma unroll
            for (int i = 0; i < 4; ++i)
                #pragma unroll
                for (int j = 0; j < 8; ++j)
                    acc[i][j] += p[i] * cv[j];
        }
    }

    // out = main - weighted (Mt is never overwritten)
    #pragma unroll
    for (int i = 0; i < 4; ++i) {
        int m = m0 + 4 * ty + i;
        #pragma unroll
        for (int j = 0; j < 8; ++j) {
            int d = tx + 16 * j;
            out[((size_t)b * LM + m) * DD + d] = Mt[4 * ty + i][d] - acc[i][j];
        }
    }
}

extern "C" void kernel_launch(void* const* d_in, const int* in_sizes, int n_in,
                              void* d_out, int out_size, void* d_ws, size_t ws_size,
                              hipStream_t stream) {
    const float* ctx = (const float*)d_in[0];  // (B, Lc, D)
    const float* mn  = (const float*)d_in[1];  // (B, Lm, D)
    float* out = (float*)d_out;                // (B, Lm, D)
    float* Lg  = (float*)d_ws;                 // B*Lc floats = 64 KB

    int nL = BATCH * LC;
    zero_kernel<<<(nL + 255) / 256, 256, 0, stream>>>(Lg, nL);
    stats_kernel<<<BATCH * (LC / 64) * MCHUNKS, 256, 0, stream>>>(ctx, mn, Lg);
    attend_kernel<<<BATCH * (LM / 64), 256, 0, stream>>>(ctx, mn, Lg, out);
}

// Round 2
// 142.107 us; speedup vs baseline: 4.2499x; 4.2499x over previous
//
#include <hip/hip_runtime.h>

// AlignOnlySubLayer: out[b,m,d] = main[b,m,d] - sum_c softmax_m(C·M^T)[c,m] * C[c,d]
// B=8, Lc=Lm=2048, D=128, fp32 in/out. bf16 MFMA (16x16x32) for both GEMM phases.
// Pass 1 (stats): L[b,c] = sum_m exp(S[b,c,m] - 40)    (constant-shift softmax; safe)
// Pass 2 (attend): out = main - sum_c (exp(S-40)/L[c]) * C[c,:]

#define BATCH 8
#define L_SEQ 2048
#define DD 128
#define SHIFT 40.0f
#define LDA 136  // bf16 row stride (272 B = 17*16: 16B-aligned rows, uniform bank spread)

typedef __attribute__((ext_vector_type(8))) short bf16x8;   // 8 bf16 = 4 VGPRs
typedef __attribute__((ext_vector_type(4))) float f32x4;    // MFMA 16x16 accumulator

__device__ __forceinline__ short f2bf(float f) {
    // round-to-nearest bf16 via bit trick (no NaN/Inf in this problem)
    unsigned u = __builtin_bit_cast(unsigned, f);
    return (short)((u + 0x8000u) >> 16);
}

// Stage a tile of fp32 (rows of 128) from global into LDS bf16 with row stride LDA.
// Coalesced: consecutive threads read consecutive 32B; one ds_write_b128 per 8 elts.
template <int NT>
__device__ __forceinline__ void stage_tile(short* __restrict__ dst,
                                           const float* __restrict__ src,
                                           int nelts, int t) {
    for (int base = 0; base < nelts; base += NT * 8) {
        int flat = base + t * 8;
        const float4* p = (const float4*)(src + flat);
        float4 v0 = p[0];
        float4 v1 = p[1];
        bf16x8 s;
        s[0] = f2bf(v0.x); s[1] = f2bf(v0.y); s[2] = f2bf(v0.z); s[3] = f2bf(v0.w);
        s[4] = f2bf(v1.x); s[5] = f2bf(v1.y); s[6] = f2bf(v1.z); s[7] = f2bf(v1.w);
        int row = flat >> 7;
        int col = flat & 127;
        *(bf16x8*)&dst[row * LDA + col] = s;
    }
}

__global__ __launch_bounds__(256) void zero_kernel(float* __restrict__ p, int n) {
    int i = blockIdx.x * 256 + threadIdx.x;
    if (i < n) p[i] = 0.0f;
}

// grid = BATCH * 32 c-tiles * 4 m-chunks = 1024 blocks, 256 threads (4 waves).
// LDS 34.8 KB -> 4 blocks/CU = 16 waves/CU. Wave w owns c-rows [w*16, w*16+16).
__global__ __launch_bounds__(256, 4) void stats_kernel(const float* __restrict__ ctx,
                                                       const float* __restrict__ mn,
                                                       float* __restrict__ Lg) {
    __shared__ short Cs[64 * LDA];
    __shared__ short Ms[64 * LDA];

    int bid = blockIdx.x;
    int mc = bid & 3;
    int ct = (bid >> 2) & 31;
    int b  = bid >> 7;
    int t = threadIdx.x;
    int w = t >> 6;
    int l = t & 63;
    int a15 = l & 15;
    int q = l >> 4;

    stage_tile<256>(Cs, ctx + ((size_t)b * L_SEQ + ct * 64) * DD, 64 * DD, t);

    float ls[4] = {0.f, 0.f, 0.f, 0.f};
    for (int mt = 0; mt < 8; ++mt) {
        __syncthreads();  // protect Ms from previous-iteration readers
        int m0 = (mc * 8 + mt) * 64;
        stage_tile<256>(Ms, mn + ((size_t)b * L_SEQ + m0) * DD, 64 * DD, t);
        __syncthreads();

        // S[c][m]: A = C rows (w*16..), B = M rows as [n=m][k=d]. 16 MFMA/wave.
        f32x4 acc[4] = {{0.f,0.f,0.f,0.f},{0.f,0.f,0.f,0.f},{0.f,0.f,0.f,0.f},{0.f,0.f,0.f,0.f}};
        #pragma unroll
        for (int ks = 0; ks < 4; ++ks) {
            int k0 = ks * 32 + q * 8;
            bf16x8 a = *(const bf16x8*)&Cs[(w * 16 + a15) * LDA + k0];
            #pragma unroll
            for (int g = 0; g < 4; ++g) {
                bf16x8 bb = *(const bf16x8*)&Ms[(g * 16 + a15) * LDA + k0];
                acc[g] = __builtin_amdgcn_mfma_f32_16x16x32_bf16(a, bb, acc[g], 0, 0, 0);
            }
        }
        // D layout: col m = l&15, row c_local = q*4 + r. Accumulate exp over m.
        #pragma unroll
        for (int g = 0; g < 4; ++g)
            #pragma unroll
            for (int r = 0; r < 4; ++r)
                ls[r] += __expf(acc[g][r] - SHIFT);
    }

    // Lanes sharing (l>>4) hold the same c: reduce over low 4 lane bits.
    #pragma unroll
    for (int r = 0; r < 4; ++r) {
        float v = ls[r];
        v += __shfl_xor(v, 1);
        v += __shfl_xor(v, 2);
        v += __shfl_xor(v, 4);
        v += __shfl_xor(v, 8);
        ls[r] = v;
    }
    if (a15 == 0) {
        int c = ct * 64 + w * 16 + q * 4;
        #pragma unroll
        for (int r = 0; r < 4; ++r)
            atomicAdd(&Lg[(size_t)b * L_SEQ + c + r], ls[r]);  // 4-way contention (m-chunks)
    }
}

// grid = BATCH * 32 m-tiles = 256 blocks, 1024 threads (16 waves).
// LDS ~105 KB -> 1 block/CU, 16 waves (50% occupancy). M_BLOCK=64, C_TILE=128, 16 c-steps.
__global__ __launch_bounds__(1024, 4) void attend_kernel(const float* __restrict__ ctx,
                                                         const float* __restrict__ mn,
                                                         const float* __restrict__ Lg,
                                                         float* __restrict__ out) {
    __shared__ short Mt[64 * LDA];    // M tile  [m][d]
    __shared__ short Cs[128 * LDA];   // C tile  [c][d]  (phase A B-operand)
    __shared__ short Ct[128 * LDA];   // C tile  [d][c]  (phase B B-operand)
    __shared__ short Ps[64 * LDA];    // P tile  [m][c]  (phase B A-operand)
    __shared__ float invLs[128];

    int bid = blockIdx.x;
    int mtile = bid & 31;
    int b = bid >> 5;
    int m0 = mtile * 64;
    int t = threadIdx.x;
    int w = t >> 6;
    int l = t & 63;
    int a15 = l & 15;
    int q = l >> 4;
    int mg = w & 3;   // m-group (16 rows) for both phases
    int pg = w >> 2;  // pair index: c-groups {2pg,2pg+1} in phase A, d-groups in phase B

    stage_tile<1024>(Mt, mn + ((size_t)b * L_SEQ + m0) * DD, 64 * DD, t);

    f32x4 oacc[2] = {{0.f,0.f,0.f,0.f},{0.f,0.f,0.f,0.f}};

    for (int cs = 0; cs < 16; ++cs) {
        int c0 = cs * 128;
        __syncthreads();  // protect Cs/Ct/Ps/invLs from previous-iteration readers
        stage_tile<1024>(Cs, ctx + ((size_t)b * L_SEQ + c0) * DD, 128 * DD, t);
        if (t < 128) invLs[t] = 1.0f / Lg[(size_t)b * L_SEQ + c0 + t];
        __syncthreads();

        // Transpose Cs[c][d] -> Ct[d][c]: b128 row reads (uniform banks), b16 scatter
        // writes hit all 32 banks (addr word = (d0+j)*68 + cc>>1, cc = lane-contiguous).
        {
            int cc = t & 127;
            int d0 = (t >> 7) * 16;
            #pragma unroll
            for (int h = 0; h < 2; ++h) {
                bf16x8 v = *(const bf16x8*)&Cs[cc * LDA + d0 + h * 8];
                #pragma unroll
                for (int j = 0; j < 8; ++j)
                    Ct[(d0 + h * 8 + j) * LDA + cc] = v[j];
            }
        }

        // Phase A: S[m 64][c 128], wave = 16m x 32c (2 tiles share A-frags).
        f32x4 sacc[2] = {{0.f,0.f,0.f,0.f},{0.f,0.f,0.f,0.f}};
        #pragma unroll
        for (int ks = 0; ks < 4; ++ks) {
            int k0 = ks * 32 + q * 8;
            bf16x8 a = *(const bf16x8*)&Mt[(mg * 16 + a15) * LDA + k0];
            #pragma unroll
            for (int g = 0; g < 2; ++g) {
                bf16x8 bb = *(const bf16x8*)&Cs[((pg * 2 + g) * 16 + a15) * LDA + k0];
                sacc[g] = __builtin_amdgcn_mfma_f32_16x16x32_bf16(a, bb, sacc[g], 0, 0, 0);
            }
        }
        // P = exp(S-40)*invL, written to Ps[m][c] (C-layout -> A-layout via LDS).
        #pragma unroll
        for (int g = 0; g < 2; ++g) {
            int cl = (pg * 2 + g) * 16 + a15;
            float il = invLs[cl];
            #pragma unroll
            for (int r = 0; r < 4; ++r) {
                float p = __expf(sacc[g][r] - SHIFT) * il;
                Ps[(mg * 16 + q * 4 + r) * LDA + cl] = f2bf(p);
            }
        }
        __syncthreads();  // Ct + Ps complete

        // Phase B: O[m 64][d 128] += P·C, wave = 16m x 32d (2 tiles share A-frags), K=c=128.
        #pragma unroll
        for (int ks = 0; ks < 4; ++ks) {
            int k0 = ks * 32 + q * 8;
            bf16x8 a = *(const bf16x8*)&Ps[(mg * 16 + a15) * LDA + k0];
            #pragma unroll
            for (int g = 0; g < 2; ++g) {
                bf16x8 bb = *(const bf16x8*)&Ct[((pg * 2 + g) * 16 + a15) * LDA + k0];
                oacc[g] = __builtin_amdgcn_mfma_f32_16x16x32_bf16(a, bb, oacc[g], 0, 0, 0);
            }
        }
    }

    // Epilogue: out = main(fp32, exact) - O. D layout: col d = a15, row m = q*4+r.
    #pragma unroll
    for (int g = 0; g < 2; ++g) {
        int dl = (pg * 2 + g) * 16 + a15;
        #pragma unroll
        for (int r = 0; r < 4; ++r) {
            int ml = mg * 16 + q * 4 + r;
            size_t idx = ((size_t)b * L_SEQ + m0 + ml) * DD + dl;
            out[idx] = mn[idx] - oacc[g][r];
        }
    }
}

extern "C" void kernel_launch(void* const* d_in, const int* in_sizes, int n_in,
                              void* d_out, int out_size, void* d_ws, size_t ws_size,
                              hipStream_t stream) {
    const float* ctx = (const float*)d_in[0];  // (B, Lc, D)
    const float* mn  = (const float*)d_in[1];  // (B, Lm, D)
    float* out = (float*)d_out;                // (B, Lm, D)
    float* Lg  = (float*)d_ws;                 // B*Lc floats = 64 KB

    int nL = BATCH * L_SEQ;
    zero_kernel<<<(nL + 255) / 256, 256, 0, stream>>>(Lg, nL);
    stats_kernel<<<BATCH * 32 * 4, 256, 0, stream>>>(ctx, mn, Lg);
    attend_kernel<<<BATCH * 32, 1024, 0, stream>>>(ctx, mn, Lg, out);
}

// Round 3
// 126.978 us; speedup vs baseline: 4.7563x; 1.1191x over previous
//
#include <hip/hip_runtime.h>

// AlignOnlySubLayer: out[b,m,d] = main[b,m,d] - sum_c softmax_m(C·M^T)[c,m] * C[c,d]
// B=8, Lc=Lm=2048, D=128, fp32 in/out.
// Round-3 structure (needs 71.4 MB workspace; falls back to round-2 kernels if less):
//   zero : Lg = 0
//   stats: E[b,m,c] = bf16(exp(S-40)) to global; L[b,c] += column sums (fp32 regs -> atomics)
//   prep : CtL[b,d,c] = bf16(C[b,c,d] * invL[b,c])   (transpose + softmax scale, ONCE)
//   attend: out = main - E · CtL   (pure bf16-MFMA GEMM, K = c = 2048)

#define BATCH 8
#define L_SEQ 2048
#define DD 128
#define SHIFT 40.0f
#define LDA 136   // bf16 row stride for 128-wide LDS tiles
#define ESLD 72   // bf16 row stride for 64-wide E staging tile

typedef __attribute__((ext_vector_type(8))) short bf16x8;
typedef __attribute__((ext_vector_type(4))) float f32x4;

__device__ __forceinline__ short f2bf(float f) {
    unsigned u = __builtin_bit_cast(unsigned, f);
    return (short)((u + 0x8000u) >> 16);
}

// fp32 global (rows of 128) -> bf16 LDS tile with row stride LDA.
template <int NT>
__device__ __forceinline__ void stage_tile(short* __restrict__ dst,
                                           const float* __restrict__ src,
                                           int nelts, int t) {
    for (int base = 0; base < nelts; base += NT * 8) {
        int flat = base + t * 8;
        const float4* p = (const float4*)(src + flat);
        float4 v0 = p[0];
        float4 v1 = p[1];
        bf16x8 s;
        s[0] = f2bf(v0.x); s[1] = f2bf(v0.y); s[2] = f2bf(v0.z); s[3] = f2bf(v0.w);
        s[4] = f2bf(v1.x); s[5] = f2bf(v1.y); s[6] = f2bf(v1.z); s[7] = f2bf(v1.w);
        int row = flat >> 7;
        int col = flat & 127;
        *(bf16x8*)&dst[row * LDA + col] = s;
    }
}

__global__ __launch_bounds__(256) void zero_kernel(float* __restrict__ p, int n) {
    int i = blockIdx.x * 256 + threadIdx.x;
    if (i < n) p[i] = 0.0f;
}

// ---------------------------------------------------------------------------
// Fast path
// ---------------------------------------------------------------------------

// grid = BATCH * 32 c-tiles(64) * 4 m-chunks = 1024 blocks, 256 thr (4 waves).
// Wave w owns m-rows [w*16, w*16+16) of each 64-m tile; computes S^T[m][c] for 64 c.
__global__ __launch_bounds__(256, 4) void stats_kernel(const float* __restrict__ ctx,
                                                       const float* __restrict__ mn,
                                                       float* __restrict__ Lg,
                                                       short* __restrict__ Eg) {
    __shared__ short Cs[64 * LDA];
    __shared__ short Ms[64 * LDA];
    __shared__ short Es[64 * ESLD];

    int bid = blockIdx.x;
    int mc = bid & 3;
    int ct = (bid >> 2) & 31;
    int b  = bid >> 7;
    int t = threadIdx.x;
    int w = t >> 6;
    int l = t & 63;
    int a15 = l & 15;
    int q = l >> 4;

    stage_tile<256>(Cs, ctx + ((size_t)b * L_SEQ + ct * 64) * DD, 64 * DD, t);

    float ls[4] = {0.f, 0.f, 0.f, 0.f};  // per-lane partial L for c = cg*16 + a15

    for (int mt = 0; mt < 8; ++mt) {
        __syncthreads();  // protect Ms/Es from previous-iteration readers
        int m0 = (mc * 8 + mt) * 64;
        stage_tile<256>(Ms, mn + ((size_t)b * L_SEQ + m0) * DD, 64 * DD, t);
        __syncthreads();

        // D[m][c]: A = M rows (this wave's 16 m), B = C rows (all 64 c). 16 MFMA.
        f32x4 sacc[4] = {{0.f,0.f,0.f,0.f},{0.f,0.f,0.f,0.f},{0.f,0.f,0.f,0.f},{0.f,0.f,0.f,0.f}};
        #pragma unroll
        for (int ks = 0; ks < 4; ++ks) {
            int k0 = ks * 32 + q * 8;
            bf16x8 a = *(const bf16x8*)&Ms[(w * 16 + a15) * LDA + k0];
            #pragma unroll
            for (int cg = 0; cg < 4; ++cg) {
                bf16x8 bb = *(const bf16x8*)&Cs[(cg * 16 + a15) * LDA + k0];
                sacc[cg] = __builtin_amdgcn_mfma_f32_16x16x32_bf16(a, bb, sacc[cg], 0, 0, 0);
            }
        }
        // D layout: col c = cg*16 + a15, row m = q*4 + r (within wave's 16 m).
        #pragma unroll
        for (int cg = 0; cg < 4; ++cg) {
            #pragma unroll
            for (int r = 0; r < 4; ++r) {
                float e = __expf(sacc[cg][r] - SHIFT);
                ls[cg] += e;
                Es[(w * 16 + q * 4 + r) * ESLD + cg * 16 + a15] = f2bf(e);
            }
        }
        __syncthreads();
        // Coalesced store of the 64x64 E tile: [b][m][c] global, 16B/lane.
        #pragma unroll
        for (int i = 0; i < 2; ++i) {
            int flat = i * 2048 + t * 8;
            int m = flat >> 6;
            int c = flat & 63;
            bf16x8 v = *(const bf16x8*)&Es[m * ESLD + c];
            *(bf16x8*)&Eg[((size_t)b * L_SEQ + m0 + m) * L_SEQ + ct * 64 + c] = v;
        }
    }

    // Sum ls over the m direction held across q (lane bits 4-5), then atomics.
    #pragma unroll
    for (int cg = 0; cg < 4; ++cg) {
        float v = ls[cg];
        v += __shfl_xor(v, 16);
        v += __shfl_xor(v, 32);
        ls[cg] = v;
    }
    if (l < 16) {
        #pragma unroll
        for (int cg = 0; cg < 4; ++cg)
            atomicAdd(&Lg[(size_t)b * L_SEQ + ct * 64 + cg * 16 + l], ls[cg]);
    }
}

// grid = BATCH * 16 c-chunks(128) = 128 blocks, 256 thr.
// CtL[b][d][c] = bf16(C[b][c][d] / L[b][c]) via LDS transpose.
__global__ __launch_bounds__(256) void prep_kernel(const float* __restrict__ ctx,
                                                   const float* __restrict__ Lg,
                                                   short* __restrict__ CtL) {
    __shared__ short Ts[128 * LDA];
    __shared__ float invLs[128];

    int b = blockIdx.x >> 4;
    int cc = blockIdx.x & 15;
    int t = threadIdx.x;

    if (t < 128) invLs[t] = 1.0f / Lg[(size_t)b * L_SEQ + cc * 128 + t];
    __syncthreads();

    const float* src = ctx + ((size_t)b * L_SEQ + cc * 128) * DD;
    #pragma unroll
    for (int i = 0; i < 8; ++i) {
        int flat = i * 2048 + t * 8;
        int r = flat >> 7;
        int c = flat & 127;
        const float4* p = (const float4*)(src + flat);
        float4 v0 = p[0];
        float4 v1 = p[1];
        float il = invLs[r];
        bf16x8 s;
        s[0] = f2bf(v0.x * il); s[1] = f2bf(v0.y * il); s[2] = f2bf(v0.z * il); s[3] = f2bf(v0.w * il);
        s[4] = f2bf(v1.x * il); s[5] = f2bf(v1.y * il); s[6] = f2bf(v1.z * il); s[7] = f2bf(v1.w * il);
        *(bf16x8*)&Ts[r * LDA + c] = s;
    }
    __syncthreads();

    int d = t >> 1;
    int ch = (t & 1) * 64;
    #pragma unroll
    for (int i = 0; i < 8; ++i) {
        int c = ch + i * 8;
        bf16x8 v;
        #pragma unroll
        for (int j = 0; j < 8; ++j) v[j] = Ts[(c + j) * LDA + d];
        *(bf16x8*)&CtL[((size_t)b * DD + d) * L_SEQ + cc * 128 + c] = v;
    }
}

// grid = BATCH * 64 m-tiles(32) = 512 blocks (2/CU), 256 thr (4 waves).
// Pure GEMM: out[m][d] = main[m][d] - sum_c E[m][c] * CtL[d][c], K = 2048.
__global__ __launch_bounds__(256, 4) void attend_kernel(const short* __restrict__ Eg,
                                                        const short* __restrict__ CtL,
                                                        const float* __restrict__ mn,
                                                        float* __restrict__ out) {
    __shared__ short Ct[128 * LDA];  // [d][c_local]
    __shared__ short Et[32 * LDA];   // [m_local][c_local]

    int bid = blockIdx.x;
    int mtile = bid & 63;
    int b = bid >> 6;
    int m0 = mtile * 32;
    int t = threadIdx.x;
    int w = t >> 6;
    int l = t & 63;
    int a15 = l & 15;
    int q = l >> 4;

    f32x4 oacc[2][2] = {{{0.f,0.f,0.f,0.f},{0.f,0.f,0.f,0.f}},
                        {{0.f,0.f,0.f,0.f},{0.f,0.f,0.f,0.f}}};

    for (int cs = 0; cs < 16; ++cs) {
        int c0 = cs * 128;
        __syncthreads();  // protect Ct/Et from previous-iteration readers
        #pragma unroll
        for (int i = 0; i < 8; ++i) {
            int flat = i * 2048 + t * 8;
            int d = flat >> 7;
            int c = flat & 127;
            bf16x8 v = *(const bf16x8*)&CtL[((size_t)b * DD + d) * L_SEQ + c0 + c];
            *(bf16x8*)&Ct[d * LDA + c] = v;
        }
        #pragma unroll
        for (int i = 0; i < 2; ++i) {
            int flat = i * 2048 + t * 8;
            int m = flat >> 7;
            int c = flat & 127;
            bf16x8 v = *(const bf16x8*)&Eg[((size_t)b * L_SEQ + m0 + m) * L_SEQ + c0 + c];
            *(bf16x8*)&Et[m * LDA + c] = v;
        }
        __syncthreads();

        // Wave w owns d-groups {2w, 2w+1}, both m-groups. 16 MFMA, 16 b128 reads.
        #pragma unroll
        for (int ks = 0; ks < 4; ++ks) {
            int k0 = ks * 32 + q * 8;
            bf16x8 a0 = *(const bf16x8*)&Et[a15 * LDA + k0];
            bf16x8 a1 = *(const bf16x8*)&Et[(16 + a15) * LDA + k0];
            #pragma unroll
            for (int g = 0; g < 2; ++g) {
                bf16x8 bb = *(const bf16x8*)&Ct[((w * 2 + g) * 16 + a15) * LDA + k0];
                oacc[0][g] = __builtin_amdgcn_mfma_f32_16x16x32_bf16(a0, bb, oacc[0][g], 0, 0, 0);
                oacc[1][g] = __builtin_amdgcn_mfma_f32_16x16x32_bf16(a1, bb, oacc[1][g], 0, 0, 0);
            }
        }
    }

    // D layout: col d = a15 (B index), row m = q*4 + r (A index).
    #pragma unroll
    for (int mg = 0; mg < 2; ++mg) {
        #pragma unroll
        for (int g = 0; g < 2; ++g) {
            int d = (w * 2 + g) * 16 + a15;
            #pragma unroll
            for (int r = 0; r < 4; ++r) {
                int m = m0 + mg * 16 + q * 4 + r;
                size_t idx = ((size_t)b * L_SEQ + m) * DD + d;
                out[idx] = mn[idx] - oacc[mg][g][r];
            }
        }
    }
}

// ---------------------------------------------------------------------------
// Fallback path (round-2 kernels, workspace = 64 KB only)
// ---------------------------------------------------------------------------

__global__ __launch_bounds__(256, 4) void stats_fb(const float* __restrict__ ctx,
                                                   const float* __restrict__ mn,
                                                   float* __restrict__ Lg) {
    __shared__ short Cs[64 * LDA];
    __shared__ short Ms[64 * LDA];

    int bid = blockIdx.x;
    int mc = bid & 3;
    int ct = (bid >> 2) & 31;
    int b  = bid >> 7;
    int t = threadIdx.x;
    int w = t >> 6;
    int l = t & 63;
    int a15 = l & 15;
    int q = l >> 4;

    stage_tile<256>(Cs, ctx + ((size_t)b * L_SEQ + ct * 64) * DD, 64 * DD, t);

    float ls[4] = {0.f, 0.f, 0.f, 0.f};
    for (int mt = 0; mt < 8; ++mt) {
        __syncthreads();
        int m0 = (mc * 8 + mt) * 64;
        stage_tile<256>(Ms, mn + ((size_t)b * L_SEQ + m0) * DD, 64 * DD, t);
        __syncthreads();

        f32x4 acc[4] = {{0.f,0.f,0.f,0.f},{0.f,0.f,0.f,0.f},{0.f,0.f,0.f,0.f},{0.f,0.f,0.f,0.f}};
        #pragma unroll
        for (int ks = 0; ks < 4; ++ks) {
            int k0 = ks * 32 + q * 8;
            bf16x8 a = *(const bf16x8*)&Cs[(w * 16 + a15) * LDA + k0];
            #pragma unroll
            for (int g = 0; g < 4; ++g) {
                bf16x8 bb = *(const bf16x8*)&Ms[(g * 16 + a15) * LDA + k0];
                acc[g] = __builtin_amdgcn_mfma_f32_16x16x32_bf16(a, bb, acc[g], 0, 0, 0);
            }
        }
        #pragma unroll
        for (int g = 0; g < 4; ++g)
            #pragma unroll
            for (int r = 0; r < 4; ++r)
                ls[r] += __expf(acc[g][r] - SHIFT);
    }

    #pragma unroll
    for (int r = 0; r < 4; ++r) {
        float v = ls[r];
        v += __shfl_xor(v, 1);
        v += __shfl_xor(v, 2);
        v += __shfl_xor(v, 4);
        v += __shfl_xor(v, 8);
        ls[r] = v;
    }
    if (a15 == 0) {
        int c = ct * 64 + w * 16 + q * 4;
        #pragma unroll
        for (int r = 0; r < 4; ++r)
            atomicAdd(&Lg[(size_t)b * L_SEQ + c + r], ls[r]);
    }
}

__global__ __launch_bounds__(1024, 4) void attend_fb(const float* __restrict__ ctx,
                                                     const float* __restrict__ mn,
                                                     const float* __restrict__ Lg,
                                                     float* __restrict__ out) {
    __shared__ short Mt[64 * LDA];
    __shared__ short Cs[128 * LDA];
    __shared__ short Ct[128 * LDA];
    __shared__ short Ps[64 * LDA];
    __shared__ float invLs[128];

    int bid = blockIdx.x;
    int mtile = bid & 31;
    int b = bid >> 5;
    int m0 = mtile * 64;
    int t = threadIdx.x;
    int w = t >> 6;
    int l = t & 63;
    int a15 = l & 15;
    int q = l >> 4;
    int mg = w & 3;
    int pg = w >> 2;

    stage_tile<1024>(Mt, mn + ((size_t)b * L_SEQ + m0) * DD, 64 * DD, t);

    f32x4 oacc[2] = {{0.f,0.f,0.f,0.f},{0.f,0.f,0.f,0.f}};

    for (int cs = 0; cs < 16; ++cs) {
        int c0 = cs * 128;
        __syncthreads();
        stage_tile<1024>(Cs, ctx + ((size_t)b * L_SEQ + c0) * DD, 128 * DD, t);
        if (t < 128) invLs[t] = 1.0f / Lg[(size_t)b * L_SEQ + c0 + t];
        __syncthreads();

        {
            int cc = t & 127;
            int d0 = (t >> 7) * 16;
            #pragma unroll
            for (int h = 0; h < 2; ++h) {
                bf16x8 v = *(const bf16x8*)&Cs[cc * LDA + d0 + h * 8];
                #pragma unroll
                for (int j = 0; j < 8; ++j)
                    Ct[(d0 + h * 8 + j) * LDA + cc] = v[j];
            }
        }

        f32x4 sacc[2] = {{0.f,0.f,0.f,0.f},{0.f,0.f,0.f,0.f}};
        #pragma unroll
        for (int ks = 0; ks < 4; ++ks) {
            int k0 = ks * 32 + q * 8;
            bf16x8 a = *(const bf16x8*)&Mt[(mg * 16 + a15) * LDA + k0];
            #pragma unroll
            for (int g = 0; g < 2; ++g) {
                bf16x8 bb = *(const bf16x8*)&Cs[((pg * 2 + g) * 16 + a15) * LDA + k0];
                sacc[g] = __builtin_amdgcn_mfma_f32_16x16x32_bf16(a, bb, sacc[g], 0, 0, 0);
            }
        }
        #pragma unroll
        for (int g = 0; g < 2; ++g) {
            int cl = (pg * 2 + g) * 16 + a15;
            float il = invLs[cl];
            #pragma unroll
            for (int r = 0; r < 4; ++r) {
                float p = __expf(sacc[g][r] - SHIFT) * il;
                Ps[(mg * 16 + q * 4 + r) * LDA + cl] = f2bf(p);
            }
        }
        __syncthreads();

        #pragma unroll
        for (int ks = 0; ks < 4; ++ks) {
            int k0 = ks * 32 + q * 8;
            bf16x8 a = *(const bf16x8*)&Ps[(mg * 16 + a15) * LDA + k0];
            #pragma unroll
            for (int g = 0; g < 2; ++g) {
                bf16x8 bb = *(const bf16x8*)&Ct[((pg * 2 + g) * 16 + a15) * LDA + k0];
                oacc[g] = __builtin_amdgcn_mfma_f32_16x16x32_bf16(a, bb, oacc[g], 0, 0, 0);
            }
        }
    }

    #pragma unroll
    for (int g = 0; g < 2; ++g) {
        int dl = (pg * 2 + g) * 16 + a15;
        #pragma unroll
        for (int r = 0; r < 4; ++r) {
            int ml = mg * 16 + q * 4 + r;
            size_t idx = ((size_t)b * L_SEQ + m0 + ml) * DD + dl;
            out[idx] = mn[idx] - oacc[g][r];
        }
    }
}

// ---------------------------------------------------------------------------

extern "C" void kernel_launch(void* const* d_in, const int* in_sizes, int n_in,
                              void* d_out, int out_size, void* d_ws, size_t ws_size,
                              hipStream_t stream) {
    const float* ctx = (const float*)d_in[0];  // (B, Lc, D)
    const float* mn  = (const float*)d_in[1];  // (B, Lm, D)
    float* out = (float*)d_out;                // (B, Lm, D)

    // Workspace layout: Lg (64 KB) | CtL (4 MB) | E (64 MB)
    const size_t LG_BYTES  = (size_t)BATCH * L_SEQ * sizeof(float);
    const size_t CTL_BYTES = (size_t)BATCH * DD * L_SEQ * sizeof(short);
    const size_t E_BYTES   = (size_t)BATCH * L_SEQ * L_SEQ * sizeof(short);
    const size_t NEED = LG_BYTES + CTL_BYTES + E_BYTES;

    float* Lg = (float*)d_ws;
    int nL = BATCH * L_SEQ;
    zero_kernel<<<(nL + 255) / 256, 256, 0, stream>>>(Lg, nL);

    if (ws_size >= NEED) {
        short* CtL = (short*)((char*)d_ws + LG_BYTES);
        short* Eg  = (short*)((char*)d_ws + LG_BYTES + CTL_BYTES);
        stats_kernel<<<BATCH * 32 * 4, 256, 0, stream>>>(ctx, mn, Lg, Eg);
        prep_kernel<<<BATCH * 16, 256, 0, stream>>>(ctx, Lg, CtL);
        attend_kernel<<<BATCH * 64, 256, 0, stream>>>(Eg, CtL, mn, out);
    } else {
        stats_fb<<<BATCH * 32 * 4, 256, 0, stream>>>(ctx, mn, Lg);
        attend_fb<<<BATCH * 32, 1024, 0, stream>>>(ctx, mn, Lg, out);
    }
}

// Round 4
// 118.425 us; speedup vs baseline: 5.0998x; 1.0722x over previous
//
#include <hip/hip_runtime.h>

// AlignOnlySubLayer: out[b,m,d] = main[b,m,d] - sum_c softmax_m(C·M^T)[c,m] * C[c,d]
// B=8, Lc=Lm=2048, D=128, fp32 in/out.
// Round-4 pipeline (all bf16 intermediates chunk-XOR-swizzled; global_load_lds staging):
//   convert: Cbf/Mbf = bf16(ctx/main), swizzled; Lg = 0
//   stats  : E[b,m,c] = bf16(exp(S-40)) (swizzled); L[b,c] via register acc + atomics
//   prep   : CtL[b,d,c] = bf16(C[b,c,d]/L[b,c]) transposed + swizzled
//   attend : out = main - E · CtL   (dbuf async-staged bf16 MFMA GEMM, K=2048)
// Swizzle: within each row, 16B chunk index pc = lc ^ (row & 7). Frag reads at
// ((ks*4+q) ^ (a15&7)) then hit exactly 8 words/bank (uniform) per ds_read_b128.

#define BATCH 8
#define L_SEQ 2048
#define DD 128
#define SHIFT 40.0f
#define LDA 136   // fallback/prep padded stride
#define ESLD 80   // stats E-staging stride (160 B: 16B-aligned, ~uniform banks)

typedef __attribute__((ext_vector_type(8))) short bf16x8;
typedef __attribute__((ext_vector_type(4))) short bf16x4;
typedef __attribute__((ext_vector_type(4))) float f32x4;

__device__ __forceinline__ short f2bf(float f) {
    unsigned u = __builtin_bit_cast(unsigned, f);
    return (short)((u + 0x8000u) >> 16);
}

// Async global->LDS, 16 B per lane. LDS dest = uniform base + lane*16.
__device__ __forceinline__ void gl2lds16(const short* g, short* l) {
    __builtin_amdgcn_global_load_lds(
        (const __attribute__((address_space(1))) unsigned int*)g,
        (__attribute__((address_space(3))) unsigned int*)l, 16, 0, 0);
}

// fp32 global (rows of 128) -> bf16 LDS tile, stride LDA (fallback path only).
template <int NT>
__device__ __forceinline__ void stage_tile(short* __restrict__ dst,
                                           const float* __restrict__ src,
                                           int nelts, int t) {
    for (int base = 0; base < nelts; base += NT * 8) {
        int flat = base + t * 8;
        const float4* p = (const float4*)(src + flat);
        float4 v0 = p[0];
        float4 v1 = p[1];
        bf16x8 s;
        s[0] = f2bf(v0.x); s[1] = f2bf(v0.y); s[2] = f2bf(v0.z); s[3] = f2bf(v0.w);
        s[4] = f2bf(v1.x); s[5] = f2bf(v1.y); s[6] = f2bf(v1.z); s[7] = f2bf(v1.w);
        int row = flat >> 7;
        int col = flat & 127;
        *(bf16x8*)&dst[row * LDA + col] = s;
    }
}

__global__ __launch_bounds__(256) void zero_kernel(float* __restrict__ p, int n) {
    int i = blockIdx.x * 256 + threadIdx.x;
    if (i < n) p[i] = 0.0f;
}

// ---------------------------------------------------------------------------
// Fast path
// ---------------------------------------------------------------------------

// grid = 2048 blocks x 256: one 16B chunk per thread for C and M; also zeros Lg.
__global__ __launch_bounds__(256) void convert_kernel(const float* __restrict__ ctx,
                                                      const float* __restrict__ mn,
                                                      short* __restrict__ Cbf,
                                                      short* __restrict__ Mbf,
                                                      float* __restrict__ Lg) {
    int tid = blockIdx.x * 256 + threadIdx.x;
    if (tid < BATCH * L_SEQ) Lg[tid] = 0.0f;
    const int half = BATCH * L_SEQ * DD / 8;  // chunks per tensor
    int id = tid;
    const float* src;
    short* dst;
    if (id < half) { src = ctx; dst = Cbf; }
    else           { id -= half; src = mn; dst = Mbf; }
    int row = id >> 4;
    int lc = id & 15;
    const float4* p = (const float4*)(src + ((size_t)row << 7) + lc * 8);
    float4 v0 = p[0];
    float4 v1 = p[1];
    bf16x8 s;
    s[0] = f2bf(v0.x); s[1] = f2bf(v0.y); s[2] = f2bf(v0.z); s[3] = f2bf(v0.w);
    s[4] = f2bf(v1.x); s[5] = f2bf(v1.y); s[6] = f2bf(v1.z); s[7] = f2bf(v1.w);
    int pc = (lc & 8) | ((lc ^ row) & 7);  // swizzle low 3 chunk bits by row&7
    *(bf16x8*)&dst[((size_t)row << 7) + pc * 8] = s;
}

// grid = 8 b * 32 ct * 4 mc = 1024 blocks, 256 thr (4 waves). LDS 42 KB -> 3 blocks/CU.
// Orientation D[c][m]: A = C rows (wave's 16 c), B = M rows. Lane holds 4 contiguous c.
__global__ __launch_bounds__(256, 3) void stats_kernel(const short* __restrict__ Cbf,
                                                       const short* __restrict__ Mbf,
                                                       float* __restrict__ Lg,
                                                       short* __restrict__ Eg) {
    __shared__ short Cs[64 * 128];
    __shared__ short Ms[64 * 128];
    __shared__ short Es[64 * ESLD];

    int bid = blockIdx.x;
    int mc = bid & 3;
    int ct = (bid >> 2) & 31;
    int b  = bid >> 7;
    int t = threadIdx.x;
    int w = t >> 6;
    int l = t & 63;
    int a15 = l & 15;
    int q = l >> 4;
    int h = a15 & 7;

    {   // issue Cs (once) + Ms(tile 0): 16 insts each, 4 per wave
        const short* gC = Cbf + ((size_t)(b * L_SEQ + ct * 64)) * DD;
        const short* gM = Mbf + ((size_t)(b * L_SEQ + mc * 512)) * DD;
        #pragma unroll
        for (int ii = 0; ii < 4; ++ii) {
            int inst = w * 4 + ii;
            gl2lds16(gC + inst * 512 + l * 8, Cs + inst * 512);
            gl2lds16(gM + inst * 512 + l * 8, Ms + inst * 512);
        }
    }

    float ls[4] = {0.f, 0.f, 0.f, 0.f};  // partial L for c = ct*64 + w*16 + q*4 + r

    for (int mt = 0; mt < 8; ++mt) {
        int m0 = mc * 512 + mt * 64;
        __syncthreads();  // drains async loads (Cs + Ms(mt)); prior Es-store reads done

        f32x4 sacc[4] = {{0.f,0.f,0.f,0.f},{0.f,0.f,0.f,0.f},{0.f,0.f,0.f,0.f},{0.f,0.f,0.f,0.f}};
        #pragma unroll
        for (int ks = 0; ks < 4; ++ks) {
            int aoff = ((ks * 4 + q) ^ h) * 8;
            bf16x8 a = *(const bf16x8*)&Cs[(w * 16 + a15) * 128 + aoff];
            #pragma unroll
            for (int g = 0; g < 4; ++g) {
                bf16x8 bb = *(const bf16x8*)&Ms[(g * 16 + a15) * 128 + aoff];
                sacc[g] = __builtin_amdgcn_mfma_f32_16x16x32_bf16(a, bb, sacc[g], 0, 0, 0);
            }
        }
        // D: row c = q*4+r (contiguous per lane), col m = g*16+a15 -> b64 writes to Es[m][c]
        #pragma unroll
        for (int g = 0; g < 4; ++g) {
            bf16x4 pk;
            #pragma unroll
            for (int r = 0; r < 4; ++r) {
                float e = __expf(sacc[g][r] - SHIFT);
                ls[r] += e;
                pk[r] = f2bf(e);
            }
            *(bf16x4*)&Es[(g * 16 + a15) * ESLD + w * 16 + q * 4] = pk;
        }
        __syncthreads();  // Es complete; Ms(mt) frag reads done

        if (mt < 7) {  // async-issue next M tile; drains at next iteration's barrier
            const short* gM = Mbf + ((size_t)(b * L_SEQ + m0 + 64)) * DD;
            #pragma unroll
            for (int ii = 0; ii < 4; ++ii) {
                int inst = w * 4 + ii;
                gl2lds16(gM + inst * 512 + l * 8, Ms + inst * 512);
            }
        }
        // Store 64x64 E tile, swizzled chunks, coalesced b128 (overlaps the async loads).
        #pragma unroll
        for (int i = 0; i < 2; ++i) {
            int flat = i * 2048 + t * 8;
            int ml = flat >> 6;
            int cl = flat & 63;
            bf16x8 v = *(const bf16x8*)&Es[ml * ESLD + cl];
            int pcr = (cl >> 3) ^ (ml & 7);
            *(bf16x8*)&Eg[((size_t)(b * L_SEQ + m0 + ml)) * L_SEQ + ct * 64 + pcr * 8] = v;
        }
    }

    #pragma unroll
    for (int r = 0; r < 4; ++r) {
        float v = ls[r];
        v += __shfl_xor(v, 1);
        v += __shfl_xor(v, 2);
        v += __shfl_xor(v, 4);
        v += __shfl_xor(v, 8);
        ls[r] = v;
    }
    if (a15 == 0) {
        int c = ct * 64 + w * 16 + q * 4;
        #pragma unroll
        for (int r = 0; r < 4; ++r)
            atomicAdd(&Lg[(size_t)b * L_SEQ + c + r], ls[r]);  // 4-way (mc) contention
    }
}

// grid = 8 b * 16 cc = 128 blocks, 256 thr. CtL[b][d][c] = bf16(C/L), swizzled by d&7.
__global__ __launch_bounds__(256) void prep_kernel(const float* __restrict__ ctx,
                                                   const float* __restrict__ Lg,
                                                   short* __restrict__ CtL) {
    __shared__ short Ts[128 * LDA];
    __shared__ float invLs[128];

    int b = blockIdx.x >> 4;
    int cc = blockIdx.x & 15;
    int t = threadIdx.x;

    if (t < 128) invLs[t] = 1.0f / Lg[(size_t)b * L_SEQ + cc * 128 + t];
    __syncthreads();

    const float* src = ctx + ((size_t)(b * L_SEQ + cc * 128)) * DD;
    #pragma unroll
    for (int i = 0; i < 8; ++i) {
        int flat = i * 2048 + t * 8;
        int r = flat >> 7;
        int c = flat & 127;
        const float4* p = (const float4*)(src + flat);
        float4 v0 = p[0];
        float4 v1 = p[1];
        float il = invLs[r];
        bf16x8 s;
        s[0] = f2bf(v0.x * il); s[1] = f2bf(v0.y * il); s[2] = f2bf(v0.z * il); s[3] = f2bf(v0.w * il);
        s[4] = f2bf(v1.x * il); s[5] = f2bf(v1.y * il); s[6] = f2bf(v1.z * il); s[7] = f2bf(v1.w * il);
        *(bf16x8*)&Ts[r * LDA + c] = s;
    }
    __syncthreads();

    int d = t >> 1;
    int ch = (t & 1) * 64;
    int key = d & 7;
    #pragma unroll
    for (int i = 0; i < 8; ++i) {
        int c = ch + i * 8;
        bf16x8 v;
        #pragma unroll
        for (int j = 0; j < 8; ++j) v[j] = Ts[(c + j) * LDA + d];
        int pc = cc * 16 + (ch >> 3) + (i ^ key);
        *(bf16x8*)&CtL[((size_t)(b * DD + d)) * L_SEQ + pc * 8] = v;
    }
}

// grid = 8 b * 64 m-tiles(32) = 512 blocks, 256 thr. LDS 80 KB dbuf -> 2 blocks/CU.
// One barrier per c-step: issue next buffer right after drain, compute current.
__global__ __launch_bounds__(256, 2) void attend_kernel(const short* __restrict__ Eg,
                                                        const short* __restrict__ CtL,
                                                        const float* __restrict__ mn,
                                                        float* __restrict__ out) {
    __shared__ short Et2[2][32 * 128];
    __shared__ short Ct2[2][128 * 128];

    int bid = blockIdx.x;
    int mtile = bid & 63;
    int b = bid >> 6;
    int m0 = mtile * 32;
    int t = threadIdx.x;
    int w = t >> 6;
    int l = t & 63;
    int a15 = l & 15;
    int q = l >> 4;
    int h = a15 & 7;
    int lcc = l & 15;

    f32x4 acc[2][2] = {{{0.f,0.f,0.f,0.f},{0.f,0.f,0.f,0.f}},
                       {{0.f,0.f,0.f,0.f},{0.f,0.f,0.f,0.f}}};

    // issue buffer 0 (c-window 0): Et 8 insts (2/wave), Ct 32 insts (8/wave)
    #pragma unroll
    for (int ii = 0; ii < 2; ++ii) {
        int inst = w * 2 + ii;
        gl2lds16(Eg + ((size_t)(b * L_SEQ + m0 + inst * 4 + q)) * L_SEQ + lcc * 8,
                 &Et2[0][inst * 512]);
    }
    #pragma unroll
    for (int ii = 0; ii < 8; ++ii) {
        int inst = w * 8 + ii;
        gl2lds16(CtL + ((size_t)(b * DD + inst * 4 + q)) * L_SEQ + lcc * 8,
                 &Ct2[0][inst * 512]);
    }

    for (int cs = 0; cs < 16; ++cs) {
        int bp = cs & 1;
        __syncthreads();  // drains loads into buf bp; buf bp^1 readers finished last iter

        if (cs < 15) {  // issue next window into the other buffer; flies during compute
            int c0 = (cs + 1) * 128;
            #pragma unroll
            for (int ii = 0; ii < 2; ++ii) {
                int inst = w * 2 + ii;
                gl2lds16(Eg + ((size_t)(b * L_SEQ + m0 + inst * 4 + q)) * L_SEQ + c0 + lcc * 8,
                         &Et2[bp ^ 1][inst * 512]);
            }
            #pragma unroll
            for (int ii = 0; ii < 8; ++ii) {
                int inst = w * 8 + ii;
                gl2lds16(CtL + ((size_t)(b * DD + inst * 4 + q)) * L_SEQ + c0 + lcc * 8,
                         &Ct2[bp ^ 1][inst * 512]);
            }
        }

        const short* EtB = Et2[bp];
        const short* CtB = Ct2[bp];
        #pragma unroll
        for (int ks = 0; ks < 4; ++ks) {
            int aoff = ((ks * 4 + q) ^ h) * 8;
            bf16x8 a0 = *(const bf16x8*)&EtB[a15 * 128 + aoff];
            bf16x8 a1 = *(const bf16x8*)&EtB[(16 + a15) * 128 + aoff];
            bf16x8 b0 = *(const bf16x8*)&CtB[((w * 2 + 0) * 16 + a15) * 128 + aoff];
            bf16x8 b1 = *(const bf16x8*)&CtB[((w * 2 + 1) * 16 + a15) * 128 + aoff];
            acc[0][0] = __builtin_amdgcn_mfma_f32_16x16x32_bf16(a0, b0, acc[0][0], 0, 0, 0);
            acc[0][1] = __builtin_amdgcn_mfma_f32_16x16x32_bf16(a0, b1, acc[0][1], 0, 0, 0);
            acc[1][0] = __builtin_amdgcn_mfma_f32_16x16x32_bf16(a1, b0, acc[1][0], 0, 0, 0);
            acc[1][1] = __builtin_amdgcn_mfma_f32_16x16x32_bf16(a1, b1, acc[1][1], 0, 0, 0);
        }
    }

    // Epilogue: out = main(fp32) - O. D: col d = a15, row m = q*4+r.
    #pragma unroll
    for (int mg = 0; mg < 2; ++mg) {
        #pragma unroll
        for (int g = 0; g < 2; ++g) {
            int d = (w * 2 + g) * 16 + a15;
            #pragma unroll
            for (int r = 0; r < 4; ++r) {
                int m = m0 + mg * 16 + q * 4 + r;
                size_t idx = ((size_t)(b * L_SEQ + m)) * DD + d;
                out[idx] = mn[idx] - acc[mg][g][r];
            }
        }
    }
}

// ---------------------------------------------------------------------------
// Fallback path (round-2 kernels, tiny workspace)
// ---------------------------------------------------------------------------

__global__ __launch_bounds__(256, 4) void stats_fb(const float* __restrict__ ctx,
                                                   const float* __restrict__ mn,
                                                   float* __restrict__ Lg) {
    __shared__ short Cs[64 * LDA];
    __shared__ short Ms[64 * LDA];

    int bid = blockIdx.x;
    int mc = bid & 3;
    int ct = (bid >> 2) & 31;
    int b  = bid >> 7;
    int t = threadIdx.x;
    int w = t >> 6;
    int l = t & 63;
    int a15 = l & 15;
    int q = l >> 4;

    stage_tile<256>(Cs, ctx + ((size_t)b * L_SEQ + ct * 64) * DD, 64 * DD, t);

    float ls[4] = {0.f, 0.f, 0.f, 0.f};
    for (int mt = 0; mt < 8; ++mt) {
        __syncthreads();
        int m0 = (mc * 8 + mt) * 64;
        stage_tile<256>(Ms, mn + ((size_t)b * L_SEQ + m0) * DD, 64 * DD, t);
        __syncthreads();

        f32x4 acc[4] = {{0.f,0.f,0.f,0.f},{0.f,0.f,0.f,0.f},{0.f,0.f,0.f,0.f},{0.f,0.f,0.f,0.f}};
        #pragma unroll
        for (int ks = 0; ks < 4; ++ks) {
            int k0 = ks * 32 + q * 8;
            bf16x8 a = *(const bf16x8*)&Cs[(w * 16 + a15) * LDA + k0];
            #pragma unroll
            for (int g = 0; g < 4; ++g) {
                bf16x8 bb = *(const bf16x8*)&Ms[(g * 16 + a15) * LDA + k0];
                acc[g] = __builtin_amdgcn_mfma_f32_16x16x32_bf16(a, bb, acc[g], 0, 0, 0);
            }
        }
        #pragma unroll
        for (int g = 0; g < 4; ++g)
            #pragma unroll
            for (int r = 0; r < 4; ++r)
                ls[r] += __expf(acc[g][r] - SHIFT);
    }

    #pragma unroll
    for (int r = 0; r < 4; ++r) {
        float v = ls[r];
        v += __shfl_xor(v, 1);
        v += __shfl_xor(v, 2);
        v += __shfl_xor(v, 4);
        v += __shfl_xor(v, 8);
        ls[r] = v;
    }
    if (a15 == 0) {
        int c = ct * 64 + w * 16 + q * 4;
        #pragma unroll
        for (int r = 0; r < 4; ++r)
            atomicAdd(&Lg[(size_t)b * L_SEQ + c + r], ls[r]);
    }
}

__global__ __launch_bounds__(1024, 4) void attend_fb(const float* __restrict__ ctx,
                                                     const float* __restrict__ mn,
                                                     const float* __restrict__ Lg,
                                                     float* __restrict__ out) {
    __shared__ short Mt[64 * LDA];
    __shared__ short Cs[128 * LDA];
    __shared__ short Ct[128 * LDA];
    __shared__ short Ps[64 * LDA];
    __shared__ float invLs[128];

    int bid = blockIdx.x;
    int mtile = bid & 31;
    int b = bid >> 5;
    int m0 = mtile * 64;
    int t = threadIdx.x;
    int w = t >> 6;
    int l = t & 63;
    int a15 = l & 15;
    int q = l >> 4;
    int mg = w & 3;
    int pg = w >> 2;

    stage_tile<1024>(Mt, mn + ((size_t)b * L_SEQ + m0) * DD, 64 * DD, t);

    f32x4 oacc[2] = {{0.f,0.f,0.f,0.f},{0.f,0.f,0.f,0.f}};

    for (int cs = 0; cs < 16; ++cs) {
        int c0 = cs * 128;
        __syncthreads();
        stage_tile<1024>(Cs, ctx + ((size_t)b * L_SEQ + c0) * DD, 128 * DD, t);
        if (t < 128) invLs[t] = 1.0f / Lg[(size_t)b * L_SEQ + c0 + t];
        __syncthreads();

        {
            int cc = t & 127;
            int d0 = (t >> 7) * 16;
            #pragma unroll
            for (int hh = 0; hh < 2; ++hh) {
                bf16x8 v = *(const bf16x8*)&Cs[cc * LDA + d0 + hh * 8];
                #pragma unroll
                for (int j = 0; j < 8; ++j)
                    Ct[(d0 + hh * 8 + j) * LDA + cc] = v[j];
            }
        }

        f32x4 sacc[2] = {{0.f,0.f,0.f,0.f},{0.f,0.f,0.f,0.f}};
        #pragma unroll
        for (int ks = 0; ks < 4; ++ks) {
            int k0 = ks * 32 + q * 8;
            bf16x8 a = *(const bf16x8*)&Mt[(mg * 16 + a15) * LDA + k0];
            #pragma unroll
            for (int g = 0; g < 2; ++g) {
                bf16x8 bb = *(const bf16x8*)&Cs[((pg * 2 + g) * 16 + a15) * LDA + k0];
                sacc[g] = __builtin_amdgcn_mfma_f32_16x16x32_bf16(a, bb, sacc[g], 0, 0, 0);
            }
        }
        #pragma unroll
        for (int g = 0; g < 2; ++g) {
            int cl = (pg * 2 + g) * 16 + a15;
            float il = invLs[cl];
            #pragma unroll
            for (int r = 0; r < 4; ++r) {
                float p = __expf(sacc[g][r] - SHIFT) * il;
                Ps[(mg * 16 + q * 4 + r) * LDA + cl] = f2bf(p);
            }
        }
        __syncthreads();

        #pragma unroll
        for (int ks = 0; ks < 4; ++ks) {
            int k0 = ks * 32 + q * 8;
            bf16x8 a = *(const bf16x8*)&Ps[(mg * 16 + a15) * LDA + k0];
            #pragma unroll
            for (int g = 0; g < 2; ++g) {
                bf16x8 bb = *(const bf16x8*)&Ct[((pg * 2 + g) * 16 + a15) * LDA + k0];
                oacc[g] = __builtin_amdgcn_mfma_f32_16x16x32_bf16(a, bb, oacc[g], 0, 0, 0);
            }
        }
    }

    #pragma unroll
    for (int g = 0; g < 2; ++g) {
        int dl = (pg * 2 + g) * 16 + a15;
        #pragma unroll
        for (int r = 0; r < 4; ++r) {
            int ml = mg * 16 + q * 4 + r;
            size_t idx = ((size_t)b * L_SEQ + m0 + ml) * DD + dl;
            out[idx] = mn[idx] - oacc[g][r];
        }
    }
}

// ---------------------------------------------------------------------------

extern "C" void kernel_launch(void* const* d_in, const int* in_sizes, int n_in,
                              void* d_out, int out_size, void* d_ws, size_t ws_size,
                              hipStream_t stream) {
    const float* ctx = (const float*)d_in[0];  // (B, Lc, D)
    const float* mn  = (const float*)d_in[1];  // (B, Lm, D)
    float* out = (float*)d_out;                // (B, Lm, D)

    // Workspace: Lg 64 KB | Cbf 4 MB | Mbf 4 MB | CtL 4 MB | E 64 MB
    const size_t LG_BYTES = (size_t)BATCH * L_SEQ * sizeof(float);
    const size_t BF_BYTES = (size_t)BATCH * L_SEQ * DD * sizeof(short);
    const size_t E_BYTES  = (size_t)BATCH * L_SEQ * L_SEQ * sizeof(short);
    const size_t NEED = LG_BYTES + 3 * BF_BYTES + E_BYTES;

    float* Lg = (float*)d_ws;

    if (ws_size >= NEED) {
        short* Cbf = (short*)((char*)d_ws + LG_BYTES);
        short* Mbf = (short*)((char*)d_ws + LG_BYTES + BF_BYTES);
        short* CtL = (short*)((char*)d_ws + LG_BYTES + 2 * BF_BYTES);
        short* Eg  = (short*)((char*)d_ws + LG_BYTES + 3 * BF_BYTES);
        convert_kernel<<<2048, 256, 0, stream>>>(ctx, mn, Cbf, Mbf, Lg);
        stats_kernel<<<BATCH * 32 * 4, 256, 0, stream>>>(Cbf, Mbf, Lg, Eg);
        prep_kernel<<<BATCH * 16, 256, 0, stream>>>(ctx, Lg, CtL);
        attend_kernel<<<BATCH * 64, 256, 0, stream>>>(Eg, CtL, mn, out);
    } else {
        int nL = BATCH * L_SEQ;
        zero_kernel<<<(nL + 255) / 256, 256, 0, stream>>>(Lg, nL);
        stats_fb<<<BATCH * 32 * 4, 256, 0, stream>>>(ctx, mn, Lg);
        attend_fb<<<BATCH * 32, 1024, 0, stream>>>(ctx, mn, Lg, out);
    }
}